// Round 21
// baseline (124.733 us; speedup 1.0000x reference)
//
#include <hip/hip_runtime.h>
#include <stdint.h>

#define BATCH 4
#define CINCH 3
#define HIN 128
#define WIN 128
#define NN 4096      // 64*64 output nodes per batch
#define CF 64        // feature channels
#define KNN 7

typedef unsigned short u16;
typedef unsigned u32;
typedef unsigned long long u64;
typedef __attribute__((ext_vector_type(8))) short bf16x8;
typedef __attribute__((ext_vector_type(4))) float f32x4;

// ---------------------------------------------------------------- helpers
__device__ __forceinline__ u64 u64min(u64 a, u64 b) { return a < b ? a : b; }
__device__ __forceinline__ u32 u32min(u32 a, u32 b) { return a < b ? a : b; }

__device__ __forceinline__ u32 med3_u32(u32 a, u32 b, u32 c) {
    u32 d;
    asm("v_med3_u32 %0, %1, %2, %3" : "=v"(d) : "v"(a), "v"(b), "v"(c));
    return d;
}

// branchless sorted top-8 insert (ascending)
__device__ __forceinline__ void insert8_med3(u32* l, u32 k) {
    l[7] = med3_u32(l[6], l[7], k);
    l[6] = med3_u32(l[5], l[6], k);
    l[5] = med3_u32(l[4], l[5], k);
    l[4] = med3_u32(l[3], l[4], k);
    l[3] = med3_u32(l[2], l[3], k);
    l[2] = med3_u32(l[1], l[2], k);
    l[1] = med3_u32(l[0], l[1], k);
    l[0] = u32min(l[0], k);
}

template <int M>
__device__ __forceinline__ void insertM64(u64* lst, u64 k) {
    u64 cur = k;
#pragma unroll
    for (int i = 0; i < M; ++i) {
        u64 lo = u64min(lst[i], cur);
        u64 hi = (lst[i] < cur) ? cur : lst[i];
        lst[i] = lo;
        cur = hi;
    }
}

// ------------------------------------------------ K1: conv + sq + tile-major quant
// One wave = one node (c == lane). No adj writes.
__global__ __launch_bounds__(256) void conv_fused_kernel(
    const float* __restrict__ x, const float* __restrict__ w,
    const float* __restrict__ bias, float* __restrict__ y,
    u16* __restrict__ ybf, float* __restrict__ sq) {
    __shared__ float ws[CF * CINCH * 9];
    __shared__ float bs[CF];
    for (int i = threadIdx.x; i < CF * CINCH * 9; i += 256) ws[i] = w[i];
    if (threadIdx.x < CF) bs[threadIdx.x] = bias[threadIdx.x];
    __syncthreads();

    int gid = blockIdx.x * 256 + threadIdx.x;   // ((b*4096)+n)*64 + c
    int c = gid & 63;                            // == lane
    int n = (gid >> 6) & (NN - 1);
    int b = gid >> 18;
    int oh = n >> 6, ow = n & 63;
    const float* xb = x + (size_t)b * CINCH * HIN * WIN;
    float acc = bs[c];
#pragma unroll
    for (int cin = 0; cin < CINCH; ++cin) {
#pragma unroll
        for (int kh = 0; kh < 3; ++kh) {
            int ih = oh * 2 - 1 + kh;
            if (ih < 0 || ih >= HIN) continue;
#pragma unroll
            for (int kw = 0; kw < 3; ++kw) {
                int iw = ow * 2 - 1 + kw;
                if (iw < 0 || iw >= WIN) continue;
                acc += xb[(cin * HIN + ih) * WIN + iw] *
                       ws[(c * CINCH + cin) * 9 + kh * 3 + kw];
            }
        }
    }
    y[(size_t)gid] = acc;

    // bf16 RNE quant -> tile-major layout:
    // ybf[((b*256 + (n>>4))*8 + (c>>3))*128 + (n&15)*8 + (c&7)]
    uint32_t u = __float_as_uint(acc);
    u16 hv = (u16)((u + 0x7fffu + ((u >> 16) & 1u)) >> 16);
    size_t ti = ((size_t)(b * 256 + (n >> 4)) * 8 + (c >> 3)) * 128 +
                (size_t)(n & 15) * 8 + (c & 7);
    ybf[ti] = hv;

    float s = acc * acc;
#pragma unroll
    for (int off = 32; off; off >>= 1) s += __shfl_xor(s, off, 64);
    if (c == 0) sq[gid >> 6] = s;
}

// ------------------------------------------------ K2: 32-row screen + zeros + rescore + ones
// 512 blocks (4 batches x 128 row-pairs), 256 threads, 4 blocks/CU.
// Halves per-CU column-stream traffic vs 16-row blocks. Per wave: 2 row-tiles,
// 2 MFMA-pairs + 2 top-8 lists per lane. sc rides the 4-slot prefetch.
// Selection per row bitwise identical to R17-R20.
__global__ __launch_bounds__(256, 4) void screen_kernel(
    const u16* __restrict__ ybf, const float* __restrict__ yf,
    const float* __restrict__ sq, float* __restrict__ adj) {
    __shared__ u32 mlds[32 * 129];       // 16.1 KB padded
    __shared__ u64 ckey[32][32];         // 8 KB
    __shared__ u32 cidx[32][32];         // 4 KB

    const int bid = blockIdx.x;
    const int b = bid >> 7;
    const int r0 = (bid & 127) << 5;     // 32 rows per block
    const int rt = (bid & 127) * 2;      // first row-tile index
    const int tid = threadIdx.x, w = tid >> 6, lane = tid & 63;
    const int lc = lane & 15, g = lane >> 4;
    const size_t nb = (size_t)b * NN;

    // B-operands: 2 row-tiles, contiguous tile-major loads
    bf16x8 rf[2][2];
    float sqr[2];
#pragma unroll
    for (int j = 0; j < 2; ++j) {
        const size_t rbj = ((size_t)(b * 256) + rt + j) * 1024 + (size_t)lane * 8;
        rf[j][0] = *(const bf16x8*)(ybf + rbj);
        rf[j][1] = *(const bf16x8*)(ybf + rbj + 512);
        sqr[j] = sq[nb + r0 + j * 16 + lc];
    }

    u32 lst[2][8];
#pragma unroll
    for (int j = 0; j < 2; ++j)
#pragma unroll
        for (int q = 0; q < 8; ++q) lst[j][q] = 0xFFFFFFFFu;

    const int c0 = w * 1024;             // this wave's column quarter
    const size_t tb = ((size_t)(b * 256) + (w << 6)) * 1024 + (size_t)lane * 8;
    const float* scp = sq + nb + c0 + g * 4;

    // zero-store streams: thread covers rows r0+(tid>>4) and r0+16+(tid>>4)
    f32x4* zrowA = (f32x4*)(adj + (nb + r0 + (tid >> 4)) * NN) + (tid & 15);
    f32x4* zrowB = (f32x4*)(adj + (nb + r0 + 16 + (tid >> 4)) * NN) + (tid & 15);
    const f32x4 zf4 = {0.f, 0.f, 0.f, 0.f};

    // prologue: fill 4 slots (tiles 0..3): 8 data loads + 4 sc loads in flight
    bf16x8 slot[4][2];
    f32x4 scs[4];
#pragma unroll
    for (int j = 0; j < 4; ++j) {
        slot[j][0] = *(const bf16x8*)(ybf + tb + (size_t)j * 1024);
        slot[j][1] = *(const bf16x8*)(ybf + tb + (size_t)j * 1024 + 512);
        scs[j] = *(const f32x4*)(scp + j * 16);
    }

    const f32x4 zro = {0.f, 0.f, 0.f, 0.f};

#define CONSUME(J, CT, REFILL)                                                  \
    {                                                                           \
        bf16x8 a0 = slot[J][0], a1 = slot[J][1];                                \
        f32x4 sc = scs[J];                                                      \
        if (REFILL) {                                                           \
            slot[J][0] = *(const bf16x8*)(ybf + tb + (size_t)((CT) + 4) * 1024);       \
            slot[J][1] = *(const bf16x8*)(ybf + tb + (size_t)((CT) + 4) * 1024 + 512); \
            scs[J] = *(const f32x4*)(scp + ((CT) + 4) * 16);                    \
        }                                                                       \
        zrowA[(CT) * 16] = zf4;                                                 \
        zrowB[(CT) * 16] = zf4;                                                 \
        _Pragma("unroll")                                                       \
        for (int j = 0; j < 2; ++j) {                                           \
            f32x4 acc = __builtin_amdgcn_mfma_f32_16x16x32_bf16(a0, rf[j][0], zro, 0, 0, 0); \
            acc = __builtin_amdgcn_mfma_f32_16x16x32_bf16(a1, rf[j][1], acc, 0, 0, 0);       \
            _Pragma("unroll")                                                   \
            for (int r = 0; r < 4; ++r) {                                       \
                float d2a = fmaxf((sqr[j] + sc[r]) - 2.f * acc[r], 0.f);        \
                u32 key = (__float_as_uint(d2a) & 0xFFFFFF00u) | (u32)((CT) * 4 + r); \
                insert8_med3(lst[j], key);                                      \
            }                                                                   \
        }                                                                       \
    }

    for (int g16 = 0; g16 < 15; ++g16) {
        const int ct0 = g16 * 4;
        CONSUME(0, ct0 + 0, 1)
        CONSUME(1, ct0 + 1, 1)
        CONSUME(2, ct0 + 2, 1)
        CONSUME(3, ct0 + 3, 1)
    }
    CONSUME(0, 60, 0)
    CONSUME(1, 61, 0)
    CONSUME(2, 62, 0)
    CONSUME(3, 63, 0)
#undef CONSUME

    // dump per-lane lists: row = j*16+lc, src = w*4+g
#pragma unroll
    for (int j = 0; j < 2; ++j)
#pragma unroll
        for (int q = 0; q < 8; ++q)
            mlds[(j * 16 + lc) * 129 + (w * 4 + g) * 8 + q] = lst[j][q];
    __syncthreads();

    // phase M: 4 threads/row (128 threads), merge 4 sources -> top-8
    if (tid < 128) {
        const int mrow = tid >> 2, s4 = tid & 3;
        u64 top8[8];
#pragma unroll
        for (int q = 0; q < 8; ++q) top8[q] = ~0ull;
#pragma unroll
        for (int s = 0; s < 4; ++s) {
            const int src = s4 * 4 + s;
            const u32 colhi = (src >> 2) * 1024 + (src & 3) * 4;
#pragma unroll
            for (int q = 0; q < 8; ++q) {
                u32 k = mlds[mrow * 129 + src * 8 + q];
                u32 idx8 = k & 0xFFu;
                u32 col = colhi + (idx8 >> 2) * 16 + (idx8 & 3);
                u64 mk = ((u64)(k & 0xFFFFFF00u) << 24) | col;
                if (mk < top8[7]) insertM64<8>(top8, mk);
            }
        }
#pragma unroll
        for (int q = 0; q < 8; ++q)
            cidx[mrow][s4 * 8 + q] = (u32)(top8[q] & 0xFFFu);
    }
    __syncthreads();

    // phase R: exact f32 rescore (trusted chain), 8 threads/row x 4 cands
    {
        const int rrow = tid >> 3, s = tid & 7;
        const float4* yr = (const float4*)(yf + (nb + r0 + rrow) * CF);
        const float sr = sq[nb + r0 + rrow];
#pragma unroll
        for (int j2 = 0; j2 < 4; ++j2) {
            const int q = s * 4 + j2;
            const u32 col = cidx[rrow][q];
            const float4* yc = (const float4*)(yf + (nb + col) * CF);
            float a = 0.f;
#pragma unroll
            for (int k = 0; k < 16; ++k) {
                float4 av = yr[k], bv = yc[k];
                a += av.x * bv.x;
                a += av.y * bv.y;
                a += av.z * bv.z;
                a += av.w * bv.w;
            }
            float d2 = (sr + sq[nb + col]) - 2.0f * a;
            float dd = sqrtf(fmaxf(d2, 0.0f));
            ckey[rrow][q] = ((u64)__float_as_uint(dd) << 32) | col;
        }
    }
    __syncthreads();

    // phase F: exact top-7 of 32 candidates
    if (tid < 32) {
        u64 t7[KNN];
#pragma unroll
        for (int q = 0; q < KNN; ++q) t7[q] = ~0ull;
#pragma unroll
        for (int q = 0; q < 32; ++q) {
            u64 k = ckey[tid][q];
            if (k < t7[KNN - 1]) insertM64<KNN>(t7, k);
        }
#pragma unroll
        for (int q = 0; q < KNN; ++q)
            cidx[tid][q] = (u32)(t7[q] & 0xFFFFFFFFu);
    }
    __syncthreads();

    // phase O: 7 ones per row (this block's zeros drained at the barriers)
    if (tid < 32 * KNN) {
        const int orow = tid / KNN, q = tid % KNN;
        u32 col = cidx[orow][q];
        adj[(nb + r0 + orow) * NN + col] = 1.0f;
    }
}

// ------------------------------------------------ launcher
extern "C" void kernel_launch(void* const* d_in, const int* in_sizes, int n_in,
                              void* d_out, int out_size, void* d_ws, size_t ws_size,
                              hipStream_t stream) {
    const float* x = (const float*)d_in[0];
    const float* w = (const float*)d_in[1];
    const float* bias = (const float*)d_in[2];

    float* y = (float*)d_out;                               // [4][4096][64]
    float* adj = (float*)d_out + (size_t)BATCH * NN * CF;   // [4][4096][4096]

    float* sq = (float*)d_ws;                               // 64 KB
    u16* ybf = (u16*)((char*)d_ws + 65536);                 // 2 MB tile-major bf16

    conv_fused_kernel<<<4096, 256, 0, stream>>>(x, w, bias, y, ybf, sq);
    screen_kernel<<<512, 256, 0, stream>>>(ybf, y, sq, adj);
}

// Round 22
// 119.129 us; speedup vs baseline: 1.0470x; 1.0470x over previous
//
#include <hip/hip_runtime.h>
#include <stdint.h>

#define BATCH 4
#define CINCH 3
#define HIN 128
#define WIN 128
#define NN 4096      // 64*64 output nodes per batch
#define CF 64        // feature channels
#define KNN 7

typedef unsigned short u16;
typedef unsigned u32;
typedef unsigned long long u64;
typedef __attribute__((ext_vector_type(8))) short bf16x8;
typedef __attribute__((ext_vector_type(4))) float f32x4;

// ---------------------------------------------------------------- helpers
__device__ __forceinline__ u64 u64min(u64 a, u64 b) { return a < b ? a : b; }
__device__ __forceinline__ u32 u32min(u32 a, u32 b) { return a < b ? a : b; }

__device__ __forceinline__ u32 med3_u32(u32 a, u32 b, u32 c) {
    u32 d;
    asm("v_med3_u32 %0, %1, %2, %3" : "=v"(d) : "v"(a), "v"(b), "v"(c));
    return d;
}

// branchless sorted top-8 insert (ascending)
__device__ __forceinline__ void insert8_med3(u32* l, u32 k) {
    l[7] = med3_u32(l[6], l[7], k);
    l[6] = med3_u32(l[5], l[6], k);
    l[5] = med3_u32(l[4], l[5], k);
    l[4] = med3_u32(l[3], l[4], k);
    l[3] = med3_u32(l[2], l[3], k);
    l[2] = med3_u32(l[1], l[2], k);
    l[1] = med3_u32(l[0], l[1], k);
    l[0] = u32min(l[0], k);
}

template <int M>
__device__ __forceinline__ void insertM64(u64* lst, u64 k) {
    u64 cur = k;
#pragma unroll
    for (int i = 0; i < M; ++i) {
        u64 lo = u64min(lst[i], cur);
        u64 hi = (lst[i] < cur) ? cur : lst[i];
        lst[i] = lo;
        cur = hi;
    }
}

// ------------------------------------------------ K1: conv + sq + tile-major quant
// One wave = one node (c == lane). No adj writes.
__global__ __launch_bounds__(256) void conv_fused_kernel(
    const float* __restrict__ x, const float* __restrict__ w,
    const float* __restrict__ bias, float* __restrict__ y,
    u16* __restrict__ ybf, float* __restrict__ sq) {
    __shared__ float ws[CF * CINCH * 9];
    __shared__ float bs[CF];
    for (int i = threadIdx.x; i < CF * CINCH * 9; i += 256) ws[i] = w[i];
    if (threadIdx.x < CF) bs[threadIdx.x] = bias[threadIdx.x];
    __syncthreads();

    int gid = blockIdx.x * 256 + threadIdx.x;   // ((b*4096)+n)*64 + c
    int c = gid & 63;                            // == lane
    int n = (gid >> 6) & (NN - 1);
    int b = gid >> 18;
    int oh = n >> 6, ow = n & 63;
    const float* xb = x + (size_t)b * CINCH * HIN * WIN;
    float acc = bs[c];
#pragma unroll
    for (int cin = 0; cin < CINCH; ++cin) {
#pragma unroll
        for (int kh = 0; kh < 3; ++kh) {
            int ih = oh * 2 - 1 + kh;
            if (ih < 0 || ih >= HIN) continue;
#pragma unroll
            for (int kw = 0; kw < 3; ++kw) {
                int iw = ow * 2 - 1 + kw;
                if (iw < 0 || iw >= WIN) continue;
                acc += xb[(cin * HIN + ih) * WIN + iw] *
                       ws[(c * CINCH + cin) * 9 + kh * 3 + kw];
            }
        }
    }
    y[(size_t)gid] = acc;

    // bf16 RNE quant -> tile-major layout:
    // ybf[((b*256 + (n>>4))*8 + (c>>3))*128 + (n&15)*8 + (c&7)]
    uint32_t u = __float_as_uint(acc);
    u16 hv = (u16)((u + 0x7fffu + ((u >> 16) & 1u)) >> 16);
    size_t ti = ((size_t)(b * 256 + (n >> 4)) * 8 + (c >> 3)) * 128 +
                (size_t)(n & 15) * 8 + (c & 7);
    ybf[ti] = hv;

    float s = acc * acc;
#pragma unroll
    for (int off = 32; off; off >>= 1) s += __shfl_xor(s, off, 64);
    if (c == 0) sq[gid >> 6] = s;
}

// ------------------------------------------------ K2: 32-row x 8-wave screen
// 512 blocks x 512 threads (2 blocks/CU, 16 waves/CU). Wave w scans 32 tiles
// (cols [w*512,(w+1)*512)) for BOTH row-tiles -> column loads serve 2 row-tiles
// (2x read-traffic cut vs R18 at the same wave count). Zeros interleaved
// (2 f32x4/thread/iter). Phase-M 8-source groups cover the same contiguous
// 1024-col quarters as R17-R21 => bitwise-identical candidate sets.
__global__ __launch_bounds__(512, 4) void screen_kernel(
    const u16* __restrict__ ybf, const float* __restrict__ yf,
    const float* __restrict__ sq, float* __restrict__ adj) {
    __shared__ u32 mlds[32 * 257];       // 32.9 KB padded: [row][src*8+q]
    __shared__ u64 ckey[32][32];         // 8 KB
    __shared__ u32 cidx[32][32];         // 4 KB

    const int bid = blockIdx.x;
    const int b = bid >> 7;
    const int r0 = (bid & 127) << 5;     // 32 rows per block
    const int rt = (bid & 127) * 2;      // first row-tile index
    const int tid = threadIdx.x, w = tid >> 6, lane = tid & 63;
    const int lc = lane & 15, g = lane >> 4;
    const size_t nb = (size_t)b * NN;

    // B-operands: 2 row-tiles, contiguous tile-major loads
    bf16x8 rf[2][2];
    float sqr[2];
#pragma unroll
    for (int j = 0; j < 2; ++j) {
        const size_t rbj = ((size_t)(b * 256) + rt + j) * 1024 + (size_t)lane * 8;
        rf[j][0] = *(const bf16x8*)(ybf + rbj);
        rf[j][1] = *(const bf16x8*)(ybf + rbj + 512);
        sqr[j] = sq[nb + r0 + j * 16 + lc];
    }

    u32 lst[2][8];
#pragma unroll
    for (int j = 0; j < 2; ++j)
#pragma unroll
        for (int q = 0; q < 8; ++q) lst[j][q] = 0xFFFFFFFFu;

    // wave's 32 tiles start at global tile w*32 (cols w*512..w*512+511)
    const size_t tb = ((size_t)(b * 256) + (w << 5)) * 1024 + (size_t)lane * 8;
    const float* scp = sq + nb + (w << 9) + g * 4;

    // zero-store streams: thread covers row r0+(tid>>4), two col halves
    f32x4* zrow = (f32x4*)(adj + (nb + r0 + (tid >> 4)) * NN) + (tid & 15);
    const f32x4 zf4 = {0.f, 0.f, 0.f, 0.f};

    // prologue: fill 4 slots (local tiles 0..3)
    bf16x8 slot[4][2];
    f32x4 scs[4];
#pragma unroll
    for (int j = 0; j < 4; ++j) {
        slot[j][0] = *(const bf16x8*)(ybf + tb + (size_t)j * 1024);
        slot[j][1] = *(const bf16x8*)(ybf + tb + (size_t)j * 1024 + 512);
        scs[j] = *(const f32x4*)(scp + j * 16);
    }

    const f32x4 zro = {0.f, 0.f, 0.f, 0.f};

#define CONSUME(J, CT, REFILL)                                                  \
    {                                                                           \
        bf16x8 a0 = slot[J][0], a1 = slot[J][1];                                \
        f32x4 sc = scs[J];                                                      \
        if (REFILL) {                                                           \
            slot[J][0] = *(const bf16x8*)(ybf + tb + (size_t)((CT) + 4) * 1024);       \
            slot[J][1] = *(const bf16x8*)(ybf + tb + (size_t)((CT) + 4) * 1024 + 512); \
            scs[J] = *(const f32x4*)(scp + ((CT) + 4) * 16);                    \
        }                                                                       \
        zrow[(CT) * 16] = zf4;                                                  \
        zrow[(CT) * 16 + 512] = zf4;                                            \
        _Pragma("unroll")                                                       \
        for (int j = 0; j < 2; ++j) {                                           \
            f32x4 acc = __builtin_amdgcn_mfma_f32_16x16x32_bf16(a0, rf[j][0], zro, 0, 0, 0); \
            acc = __builtin_amdgcn_mfma_f32_16x16x32_bf16(a1, rf[j][1], acc, 0, 0, 0);       \
            _Pragma("unroll")                                                   \
            for (int r = 0; r < 4; ++r) {                                       \
                float d2a = fmaxf((sqr[j] + sc[r]) - 2.f * acc[r], 0.f);        \
                u32 key = (__float_as_uint(d2a) & 0xFFFFFF00u) | (u32)((CT) * 4 + r); \
                insert8_med3(lst[j], key);                                      \
            }                                                                   \
        }                                                                       \
    }

    for (int g16 = 0; g16 < 7; ++g16) {
        const int ct0 = g16 * 4;
        CONSUME(0, ct0 + 0, 1)
        CONSUME(1, ct0 + 1, 1)
        CONSUME(2, ct0 + 2, 1)
        CONSUME(3, ct0 + 3, 1)
    }
    // epilogue: local tiles 28..31, no refills
    CONSUME(0, 28, 0)
    CONSUME(1, 29, 0)
    CONSUME(2, 30, 0)
    CONSUME(3, 31, 0)
#undef CONSUME

    // dump per-lane lists: row = j*16+lc, src = w*4+g (0..31)
#pragma unroll
    for (int j = 0; j < 2; ++j)
#pragma unroll
        for (int q = 0; q < 8; ++q)
            mlds[(j * 16 + lc) * 257 + (w * 4 + g) * 8 + q] = lst[j][q];
    __syncthreads();

    // phase M: 4 threads/row (128 threads), each merges 8 sources (one
    // contiguous 1024-col quarter) -> exact quarter top-8 (same as R17-R21)
    if (tid < 128) {
        const int mrow = tid >> 2, s4 = tid & 3;
        u64 top8[8];
#pragma unroll
        for (int q = 0; q < 8; ++q) top8[q] = ~0ull;
#pragma unroll
        for (int s = 0; s < 8; ++s) {
            const int src = s4 * 8 + s;
            const u32 colhi = (u32)((src >> 2) << 9) + (u32)((src & 3) << 2);
#pragma unroll
            for (int q = 0; q < 8; ++q) {
                u32 k = mlds[mrow * 257 + src * 8 + q];
                u32 idx8 = k & 0xFFu;
                u32 col = colhi + (idx8 >> 2) * 16 + (idx8 & 3);
                u64 mk = ((u64)(k & 0xFFFFFF00u) << 24) | col;
                if (mk < top8[7]) insertM64<8>(top8, mk);
            }
        }
#pragma unroll
        for (int q = 0; q < 8; ++q)
            cidx[mrow][s4 * 8 + q] = (u32)(top8[q] & 0xFFFu);
    }
    __syncthreads();

    // phase R: exact f32 rescore (trusted chain), 16 threads/row x 2 cands
    {
        const int rrow = tid >> 4, s = tid & 15;
        const float4* yr = (const float4*)(yf + (nb + r0 + rrow) * CF);
        const float sr = sq[nb + r0 + rrow];
#pragma unroll
        for (int j2 = 0; j2 < 2; ++j2) {
            const int q = s * 2 + j2;
            const u32 col = cidx[rrow][q];
            const float4* yc = (const float4*)(yf + (nb + col) * CF);
            float a = 0.f;
#pragma unroll
            for (int k = 0; k < 16; ++k) {
                float4 av = yr[k], bv = yc[k];
                a += av.x * bv.x;
                a += av.y * bv.y;
                a += av.z * bv.z;
                a += av.w * bv.w;
            }
            float d2 = (sr + sq[nb + col]) - 2.0f * a;
            float dd = sqrtf(fmaxf(d2, 0.0f));
            ckey[rrow][q] = ((u64)__float_as_uint(dd) << 32) | col;
        }
    }
    __syncthreads();

    // phase F: exact top-7 of 32 candidates
    if (tid < 32) {
        u64 t7[KNN];
#pragma unroll
        for (int q = 0; q < KNN; ++q) t7[q] = ~0ull;
#pragma unroll
        for (int q = 0; q < 32; ++q) {
            u64 k = ckey[tid][q];
            if (k < t7[KNN - 1]) insertM64<KNN>(t7, k);
        }
#pragma unroll
        for (int q = 0; q < KNN; ++q)
            cidx[tid][q] = (u32)(t7[q] & 0xFFFFFFFFu);
    }
    __syncthreads();

    // phase O: 7 ones per row (this block's zeros drained at the barriers)
    if (tid < 32 * KNN) {
        const int orow = tid / KNN, q = tid % KNN;
        u32 col = cidx[orow][q];
        adj[(nb + r0 + orow) * NN + col] = 1.0f;
    }
}

// ------------------------------------------------ launcher
extern "C" void kernel_launch(void* const* d_in, const int* in_sizes, int n_in,
                              void* d_out, int out_size, void* d_ws, size_t ws_size,
                              hipStream_t stream) {
    const float* x = (const float*)d_in[0];
    const float* w = (const float*)d_in[1];
    const float* bias = (const float*)d_in[2];

    float* y = (float*)d_out;                               // [4][4096][64]
    float* adj = (float*)d_out + (size_t)BATCH * NN * CF;   // [4][4096][4096]

    float* sq = (float*)d_ws;                               // 64 KB
    u16* ybf = (u16*)((char*)d_ws + 65536);                 // 2 MB tile-major bf16

    conv_fused_kernel<<<4096, 256, 0, stream>>>(x, w, bias, y, ybf, sq);
    screen_kernel<<<512, 512, 0, stream>>>(ybf, y, sq, adj);
}

// Round 23
// 103.075 us; speedup vs baseline: 1.2101x; 1.1558x over previous
//
#include <hip/hip_runtime.h>
#include <stdint.h>

#define BATCH 4
#define CINCH 3
#define HIN 128
#define WIN 128
#define NN 4096      // 64*64 output nodes per batch
#define CF 64        // feature channels
#define KNN 7

typedef unsigned short u16;
typedef unsigned u32;
typedef unsigned long long u64;
typedef __attribute__((ext_vector_type(8))) short bf16x8;
typedef __attribute__((ext_vector_type(4))) float f32x4;

// ---------------------------------------------------------------- helpers
__device__ __forceinline__ u64 u64min(u64 a, u64 b) { return a < b ? a : b; }
__device__ __forceinline__ u32 u32min(u32 a, u32 b) { return a < b ? a : b; }

__device__ __forceinline__ u32 med3_u32(u32 a, u32 b, u32 c) {
    u32 d;
    asm("v_med3_u32 %0, %1, %2, %3" : "=v"(d) : "v"(a), "v"(b), "v"(c));
    return d;
}

// branchless sorted top-8 insert (ascending)
__device__ __forceinline__ void insert8_med3(u32* l, u32 k) {
    l[7] = med3_u32(l[6], l[7], k);
    l[6] = med3_u32(l[5], l[6], k);
    l[5] = med3_u32(l[4], l[5], k);
    l[4] = med3_u32(l[3], l[4], k);
    l[3] = med3_u32(l[2], l[3], k);
    l[2] = med3_u32(l[1], l[2], k);
    l[1] = med3_u32(l[0], l[1], k);
    l[0] = u32min(l[0], k);
}

template <int M>
__device__ __forceinline__ void insertM64(u64* lst, u64 k) {
    u64 cur = k;
#pragma unroll
    for (int i = 0; i < M; ++i) {
        u64 lo = u64min(lst[i], cur);
        u64 hi = (lst[i] < cur) ? cur : lst[i];
        lst[i] = lo;
        cur = hi;
    }
}

// ------------------------------------------------ K1: conv + sq + tile-major quant
__global__ __launch_bounds__(256) void conv_fused_kernel(
    const float* __restrict__ x, const float* __restrict__ w,
    const float* __restrict__ bias, float* __restrict__ y,
    u16* __restrict__ ybf, float* __restrict__ sq) {
    __shared__ float ws[CF * CINCH * 9];
    __shared__ float bs[CF];
    for (int i = threadIdx.x; i < CF * CINCH * 9; i += 256) ws[i] = w[i];
    if (threadIdx.x < CF) bs[threadIdx.x] = bias[threadIdx.x];
    __syncthreads();

    int gid = blockIdx.x * 256 + threadIdx.x;   // ((b*4096)+n)*64 + c
    int c = gid & 63;                            // == lane
    int n = (gid >> 6) & (NN - 1);
    int b = gid >> 18;
    int oh = n >> 6, ow = n & 63;
    const float* xb = x + (size_t)b * CINCH * HIN * WIN;
    float acc = bs[c];
#pragma unroll
    for (int cin = 0; cin < CINCH; ++cin) {
#pragma unroll
        for (int kh = 0; kh < 3; ++kh) {
            int ih = oh * 2 - 1 + kh;
            if (ih < 0 || ih >= HIN) continue;
#pragma unroll
            for (int kw = 0; kw < 3; ++kw) {
                int iw = ow * 2 - 1 + kw;
                if (iw < 0 || iw >= WIN) continue;
                acc += xb[(cin * HIN + ih) * WIN + iw] *
                       ws[(c * CINCH + cin) * 9 + kh * 3 + kw];
            }
        }
    }
    y[(size_t)gid] = acc;

    // bf16 RNE quant -> tile-major layout:
    // ybf[((b*256 + (n>>4))*8 + (c>>3))*128 + (n&15)*8 + (c&7)]
    uint32_t u = __float_as_uint(acc);
    u16 hv = (u16)((u + 0x7fffu + ((u >> 16) & 1u)) >> 16);
    size_t ti = ((size_t)(b * 256 + (n >> 4)) * 8 + (c >> 3)) * 128 +
                (size_t)(n & 15) * 8 + (c & 7);
    ybf[ti] = hv;

    float s = acc * acc;
#pragma unroll
    for (int off = 32; off; off >>= 1) s += __shfl_xor(s, off, 64);
    if (c == 0) sq[gid >> 6] = s;
}

// ------------------------------------------------ K2: 32-row x 8-wave screen (slim)
// 512 blocks x 512 threads (2 blocks/CU, 16 waves/CU). Wave w scans 32 tiles
// (cols [w*512,(w+1)*512)) for BOTH row-tiles (halves scan traffic vs R18).
// 2-deep register pipeline keeps VGPR < 128 (R22's 4-deep likely spilled).
// Selection bitwise identical to R17-R22.
__global__ __launch_bounds__(512, 4) void screen_kernel(
    const u16* __restrict__ ybf, const float* __restrict__ yf,
    const float* __restrict__ sq, float* __restrict__ adj) {
    __shared__ u32 mlds[32 * 257];       // 32.9 KB padded: [row][src*8+q]
    __shared__ u64 ckey[32][32];         // 8 KB
    __shared__ u32 cidx[32][32];         // 4 KB

    const int bid = blockIdx.x;
    const int b = bid >> 7;
    const int r0 = (bid & 127) << 5;     // 32 rows per block
    const int rt = (bid & 127) * 2;      // first row-tile index
    const int tid = threadIdx.x, w = tid >> 6, lane = tid & 63;
    const int lc = lane & 15, g = lane >> 4;
    const size_t nb = (size_t)b * NN;

    // B-operands: 2 row-tiles, contiguous tile-major loads
    bf16x8 rf[2][2];
    float sqr[2];
#pragma unroll
    for (int j = 0; j < 2; ++j) {
        const size_t rbj = ((size_t)(b * 256) + rt + j) * 1024 + (size_t)lane * 8;
        rf[j][0] = *(const bf16x8*)(ybf + rbj);
        rf[j][1] = *(const bf16x8*)(ybf + rbj + 512);
        sqr[j] = sq[nb + r0 + j * 16 + lc];
    }

    u32 lst[2][8];
#pragma unroll
    for (int j = 0; j < 2; ++j)
#pragma unroll
        for (int q = 0; q < 8; ++q) lst[j][q] = 0xFFFFFFFFu;

    // wave's 32 tiles start at global tile w*32 (cols w*512..w*512+511)
    const size_t tb = ((size_t)(b * 256) + (w << 5)) * 1024 + (size_t)lane * 8;
    const float* scp = sq + nb + (w << 9) + g * 4;

    // zero-store stream: thread covers row r0+(tid>>4), two col halves
    f32x4* zrow = (f32x4*)(adj + (nb + r0 + (tid >> 4)) * NN) + (tid & 15);
    const f32x4 zf4 = {0.f, 0.f, 0.f, 0.f};

    // prologue: fill 2 slots (local tiles 0,1)
    bf16x8 slot[2][2];
    f32x4 scs[2];
#pragma unroll
    for (int j = 0; j < 2; ++j) {
        slot[j][0] = *(const bf16x8*)(ybf + tb + (size_t)j * 1024);
        slot[j][1] = *(const bf16x8*)(ybf + tb + (size_t)j * 1024 + 512);
        scs[j] = *(const f32x4*)(scp + j * 16);
    }

    const f32x4 zro = {0.f, 0.f, 0.f, 0.f};

#define CONSUME(J, CT, REFILL)                                                  \
    {                                                                           \
        bf16x8 a0 = slot[J][0], a1 = slot[J][1];                                \
        f32x4 sc = scs[J];                                                      \
        if (REFILL) {                                                           \
            slot[J][0] = *(const bf16x8*)(ybf + tb + (size_t)((CT) + 2) * 1024);       \
            slot[J][1] = *(const bf16x8*)(ybf + tb + (size_t)((CT) + 2) * 1024 + 512); \
            scs[J] = *(const f32x4*)(scp + ((CT) + 2) * 16);                    \
        }                                                                       \
        zrow[(CT) * 16] = zf4;                                                  \
        zrow[(CT) * 16 + 512] = zf4;                                            \
        _Pragma("unroll")                                                       \
        for (int j = 0; j < 2; ++j) {                                           \
            f32x4 acc = __builtin_amdgcn_mfma_f32_16x16x32_bf16(a0, rf[j][0], zro, 0, 0, 0); \
            acc = __builtin_amdgcn_mfma_f32_16x16x32_bf16(a1, rf[j][1], acc, 0, 0, 0);       \
            _Pragma("unroll")                                                   \
            for (int r = 0; r < 4; ++r) {                                       \
                float d2a = fmaxf((sqr[j] + sc[r]) - 2.f * acc[r], 0.f);        \
                u32 key = (__float_as_uint(d2a) & 0xFFFFFF00u) | (u32)((CT) * 4 + r); \
                insert8_med3(lst[j], key);                                      \
            }                                                                   \
        }                                                                       \
    }

    for (int g2 = 0; g2 < 15; ++g2) {
        const int ct0 = g2 * 2;
        CONSUME(0, ct0 + 0, 1)
        CONSUME(1, ct0 + 1, 1)
    }
    // epilogue: local tiles 30,31, no refills
    CONSUME(0, 30, 0)
    CONSUME(1, 31, 0)
#undef CONSUME

    // dump per-lane lists: row = j*16+lc, src = w*4+g (0..31)
#pragma unroll
    for (int j = 0; j < 2; ++j)
#pragma unroll
        for (int q = 0; q < 8; ++q)
            mlds[(j * 16 + lc) * 257 + (w * 4 + g) * 8 + q] = lst[j][q];
    __syncthreads();

    // phase M: 4 threads/row (128 threads), each merges 8 sources (one
    // contiguous 1024-col quarter) -> exact quarter top-8 (same as R17-R22)
    if (tid < 128) {
        const int mrow = tid >> 2, s4 = tid & 3;
        u64 top8[8];
#pragma unroll
        for (int q = 0; q < 8; ++q) top8[q] = ~0ull;
#pragma unroll
        for (int s = 0; s < 8; ++s) {
            const int src = s4 * 8 + s;
            const u32 colhi = (u32)((src >> 2) << 9) + (u32)((src & 3) << 2);
#pragma unroll
            for (int q = 0; q < 8; ++q) {
                u32 k = mlds[mrow * 257 + src * 8 + q];
                u32 idx8 = k & 0xFFu;
                u32 col = colhi + (idx8 >> 2) * 16 + (idx8 & 3);
                u64 mk = ((u64)(k & 0xFFFFFF00u) << 24) | col;
                if (mk < top8[7]) insertM64<8>(top8, mk);
            }
        }
#pragma unroll
        for (int q = 0; q < 8; ++q)
            cidx[mrow][s4 * 8 + q] = (u32)(top8[q] & 0xFFFu);
    }
    __syncthreads();

    // phase R: exact f32 rescore (trusted chain), 16 threads/row x 2 cands
    {
        const int rrow = tid >> 4, s = tid & 15;
        const float4* yr = (const float4*)(yf + (nb + r0 + rrow) * CF);
        const float sr = sq[nb + r0 + rrow];
#pragma unroll
        for (int j2 = 0; j2 < 2; ++j2) {
            const int q = s * 2 + j2;
            const u32 col = cidx[rrow][q];
            const float4* yc = (const float4*)(yf + (nb + col) * CF);
            float a = 0.f;
#pragma unroll
            for (int k = 0; k < 16; ++k) {
                float4 av = yr[k], bv = yc[k];
                a += av.x * bv.x;
                a += av.y * bv.y;
                a += av.z * bv.z;
                a += av.w * bv.w;
            }
            float d2 = (sr + sq[nb + col]) - 2.0f * a;
            float dd = sqrtf(fmaxf(d2, 0.0f));
            ckey[rrow][q] = ((u64)__float_as_uint(dd) << 32) | col;
        }
    }
    __syncthreads();

    // phase F: exact top-7 of 32 candidates
    if (tid < 32) {
        u64 t7[KNN];
#pragma unroll
        for (int q = 0; q < KNN; ++q) t7[q] = ~0ull;
#pragma unroll
        for (int q = 0; q < 32; ++q) {
            u64 k = ckey[tid][q];
            if (k < t7[KNN - 1]) insertM64<KNN>(t7, k);
        }
#pragma unroll
        for (int q = 0; q < KNN; ++q)
            cidx[tid][q] = (u32)(t7[q] & 0xFFFFFFFFu);
    }
    __syncthreads();

    // phase O: 7 ones per row (this block's zeros drained at the barriers)
    if (tid < 32 * KNN) {
        const int orow = tid / KNN, q = tid % KNN;
        u32 col = cidx[orow][q];
        adj[(nb + r0 + orow) * NN + col] = 1.0f;
    }
}

// ------------------------------------------------ launcher
extern "C" void kernel_launch(void* const* d_in, const int* in_sizes, int n_in,
                              void* d_out, int out_size, void* d_ws, size_t ws_size,
                              hipStream_t stream) {
    const float* x = (const float*)d_in[0];
    const float* w = (const float*)d_in[1];
    const float* bias = (const float*)d_in[2];

    float* y = (float*)d_out;                               // [4][4096][64]
    float* adj = (float*)d_out + (size_t)BATCH * NN * CF;   // [4][4096][4096]

    float* sq = (float*)d_ws;                               // 64 KB
    u16* ybf = (u16*)((char*)d_ws + 65536);                 // 2 MB tile-major bf16

    conv_fused_kernel<<<4096, 256, 0, stream>>>(x, w, bias, y, ybf, sq);
    screen_kernel<<<512, 512, 0, stream>>>(ybf, y, sq, adj);
}

// Round 24
// 96.153 us; speedup vs baseline: 1.2972x; 1.0720x over previous
//
#include <hip/hip_runtime.h>
#include <stdint.h>

#define BATCH 4
#define CINCH 3
#define HIN 128
#define WIN 128
#define NN 4096      // 64*64 output nodes per batch
#define CF 64        // feature channels
#define KNN 7

typedef unsigned short u16;
typedef unsigned u32;
typedef unsigned long long u64;
typedef __attribute__((ext_vector_type(8))) short bf16x8;
typedef __attribute__((ext_vector_type(4))) float f32x4;

// ---------------------------------------------------------------- helpers
__device__ __forceinline__ u64 u64min(u64 a, u64 b) { return a < b ? a : b; }
__device__ __forceinline__ u32 u32min(u32 a, u32 b) { return a < b ? a : b; }

__device__ __forceinline__ u32 med3_u32(u32 a, u32 b, u32 c) {
    u32 d;
    asm("v_med3_u32 %0, %1, %2, %3" : "=v"(d) : "v"(a), "v"(b), "v"(c));
    return d;
}

// branchless sorted top-8 insert (ascending)
__device__ __forceinline__ void insert8_med3(u32* l, u32 k) {
    l[7] = med3_u32(l[6], l[7], k);
    l[6] = med3_u32(l[5], l[6], k);
    l[5] = med3_u32(l[4], l[5], k);
    l[4] = med3_u32(l[3], l[4], k);
    l[3] = med3_u32(l[2], l[3], k);
    l[2] = med3_u32(l[1], l[2], k);
    l[1] = med3_u32(l[0], l[1], k);
    l[0] = u32min(l[0], k);
}

template <int M>
__device__ __forceinline__ void insertM64(u64* lst, u64 k) {
    u64 cur = k;
#pragma unroll
    for (int i = 0; i < M; ++i) {
        u64 lo = u64min(lst[i], cur);
        u64 hi = (lst[i] < cur) ? cur : lst[i];
        lst[i] = lo;
        cur = hi;
    }
}

// ------------------------------------------------ K1: conv + sq + tile-major quant
// One wave = one node (c == lane). acc chain bitwise-identical to prior rounds.
__global__ __launch_bounds__(256) void conv_fused_kernel(
    const float* __restrict__ x, const float* __restrict__ w,
    const float* __restrict__ bias, float* __restrict__ y,
    u16* __restrict__ ybf, float* __restrict__ sq) {
    __shared__ float ws[CF * CINCH * 9];
    __shared__ float bs[CF];
    for (int i = threadIdx.x; i < CF * CINCH * 9; i += 256) ws[i] = w[i];
    if (threadIdx.x < CF) bs[threadIdx.x] = bias[threadIdx.x];
    __syncthreads();

    int gid = blockIdx.x * 256 + threadIdx.x;   // ((b*4096)+n)*64 + c
    int c = gid & 63;                            // == lane
    int n = (gid >> 6) & (NN - 1);
    int b = gid >> 18;
    int oh = n >> 6, ow = n & 63;
    const float* xb = x + (size_t)b * CINCH * HIN * WIN;
    float acc = bs[c];
#pragma unroll
    for (int cin = 0; cin < CINCH; ++cin) {
#pragma unroll
        for (int kh = 0; kh < 3; ++kh) {
            int ih = oh * 2 - 1 + kh;
            if (ih < 0 || ih >= HIN) continue;
#pragma unroll
            for (int kw = 0; kw < 3; ++kw) {
                int iw = ow * 2 - 1 + kw;
                if (iw < 0 || iw >= WIN) continue;
                acc += xb[(cin * HIN + ih) * WIN + iw] *
                       ws[(c * CINCH + cin) * 9 + kh * 3 + kw];
            }
        }
    }
    y[(size_t)gid] = acc;

    // bf16 RNE quant -> tile-major layout:
    // ybf[((b*256 + (n>>4))*8 + (c>>3))*128 + (n&15)*8 + (c&7)]
    uint32_t u = __float_as_uint(acc);
    u16 hv = (u16)((u + 0x7fffu + ((u >> 16) & 1u)) >> 16);
    size_t ti = ((size_t)(b * 256 + (n >> 4)) * 8 + (c >> 3)) * 128 +
                (size_t)(n & 15) * 8 + (c & 7);
    ybf[ti] = hv;

    float s = acc * acc;
#pragma unroll
    for (int off = 32; off; off >>= 1) s += __shfl_xor(s, off, 64);
    if (c == 0) sq[gid >> 6] = s;
}

// ------------------------------------------------ K2: screen + zeros + rescore + ones
// 1024 blocks, 256 threads, 4 blocks/CU. R17's contiguous tile-major loads +
// R10's interleaved zero-store (1 f32x4/thread/iter -> block's 16 adj rows,
// draining under the select compute). Selection bitwise = R17.
__global__ __launch_bounds__(256, 4) void screen_kernel(
    const u16* __restrict__ ybf, const float* __restrict__ yf,
    const float* __restrict__ sq, float* __restrict__ adj) {
    __shared__ float sqlds[NN];          // 16 KB
    __shared__ u32 mlds[16 * 129];       // 8.25 KB
    __shared__ u64 ckey[16][32];         // 4 KB
    __shared__ u32 cidx[16][32];         // 2 KB

    const int bid = blockIdx.x;
    const int b = bid >> 8;
    const int r0 = (bid & 255) << 4;     // 16 rows per block
    const int tid = threadIdx.x, w = tid >> 6, lane = tid & 63;
    const int lc = lane & 15, g = lane >> 4;
    const size_t nb = (size_t)b * NN;

    {
        const float4* s4 = (const float4*)(sq + nb);
        float4* d4 = (float4*)sqlds;
#pragma unroll
        for (int i = 0; i < 4; ++i) d4[i * 256 + tid] = s4[i * 256 + tid];
    }

    // B-operand: this block's row-tile, contiguous tile-major loads
    const size_t rb = ((size_t)(b * 256) + (r0 >> 4)) * 1024 + (size_t)lane * 8;
    bf16x8 rf0 = *(const bf16x8*)(ybf + rb);
    bf16x8 rf1 = *(const bf16x8*)(ybf + rb + 512);
    const float sqr = sq[nb + r0 + lc];

    u32 lst[8];
#pragma unroll
    for (int q = 0; q < 8; ++q) lst[q] = 0xFFFFFFFFu;

    const int c0 = w * 1024;             // this wave's column quarter
    const size_t tb = ((size_t)(b * 256) + (w << 6)) * 1024 + (size_t)lane * 8;

    // zero-store stream: thread covers row r0+(tid>>4), one f32x4 per iter
    f32x4* zrow = (f32x4*)(adj + (nb + r0 + (tid >> 4)) * NN) + (tid & 15);
    const f32x4 zf4 = {0.f, 0.f, 0.f, 0.f};

    // prologue: fill 4 slots, 8 contiguous loads in flight
    bf16x8 slot[4][2];
#pragma unroll
    for (int j = 0; j < 4; ++j) {
        slot[j][0] = *(const bf16x8*)(ybf + tb + (size_t)j * 1024);
        slot[j][1] = *(const bf16x8*)(ybf + tb + (size_t)j * 1024 + 512);
    }

    __syncthreads();   // sqlds ready

    const f32x4 zro = {0.f, 0.f, 0.f, 0.f};

#define CONSUME(J, CT, REFILL)                                                  \
    {                                                                           \
        bf16x8 a0 = slot[J][0], a1 = slot[J][1];                                \
        if (REFILL) {                                                           \
            slot[J][0] = *(const bf16x8*)(ybf + tb + (size_t)((CT) + 4) * 1024);       \
            slot[J][1] = *(const bf16x8*)(ybf + tb + (size_t)((CT) + 4) * 1024 + 512); \
        }                                                                       \
        zrow[(CT) * 16] = zf4;  /* zero-store rides idle HBM under compute */   \
        f32x4 sc = *(const f32x4*)&sqlds[c0 + (CT) * 16 + g * 4];               \
        f32x4 acc = __builtin_amdgcn_mfma_f32_16x16x32_bf16(a0, rf0, zro, 0, 0, 0); \
        acc = __builtin_amdgcn_mfma_f32_16x16x32_bf16(a1, rf1, acc, 0, 0, 0);   \
        _Pragma("unroll")                                                       \
        for (int r = 0; r < 4; ++r) {                                           \
            float d2a = fmaxf((sqr + sc[r]) - 2.f * acc[r], 0.f);               \
            u32 key = (__float_as_uint(d2a) & 0xFFFFFF00u) | (u32)((CT) * 4 + r); \
            insert8_med3(lst, key);                                             \
        }                                                                       \
    }

    for (int g16 = 0; g16 < 15; ++g16) {
        const int ct0 = g16 * 4;
        CONSUME(0, ct0 + 0, 1)
        CONSUME(1, ct0 + 1, 1)
        CONSUME(2, ct0 + 2, 1)
        CONSUME(3, ct0 + 3, 1)
    }
    CONSUME(0, 60, 0)
    CONSUME(1, 61, 0)
    CONSUME(2, 62, 0)
    CONSUME(3, 63, 0)
#undef CONSUME

    // dump per-lane lists: row = lc, src = w*4+g
#pragma unroll
    for (int q = 0; q < 8; ++q)
        mlds[lc * 129 + (w * 4 + g) * 8 + q] = lst[q];
    __syncthreads();

    // phase M: 4 threads/row, merge 4 sources -> top-8 (trunc-key + col order)
    if (tid < 64) {
        const int mrow = tid >> 2, s4 = tid & 3;
        u64 top8[8];
#pragma unroll
        for (int q = 0; q < 8; ++q) top8[q] = ~0ull;
#pragma unroll
        for (int s = 0; s < 4; ++s) {
            const int src = s4 * 4 + s;
            const u32 colhi = (src >> 2) * 1024 + (src & 3) * 4;
#pragma unroll
            for (int q = 0; q < 8; ++q) {
                u32 k = mlds[mrow * 129 + src * 8 + q];
                u32 idx8 = k & 0xFFu;
                u32 col = colhi + (idx8 >> 2) * 16 + (idx8 & 3);
                u64 mk = ((u64)(k & 0xFFFFFF00u) << 24) | col;
                if (mk < top8[7]) insertM64<8>(top8, mk);
            }
        }
#pragma unroll
        for (int q = 0; q < 8; ++q)
            cidx[mrow][s4 * 8 + q] = (u32)(top8[q] & 0xFFFu);
    }
    __syncthreads();

    // phase R: exact f32 rescore (trusted chain), 16 threads/row x 2 cands
    {
        const int rrow = tid >> 4, s = tid & 15;
        const float4* yr = (const float4*)(yf + (nb + r0 + rrow) * CF);
        const float sr = sqlds[r0 + rrow];
#pragma unroll
        for (int j2 = 0; j2 < 2; ++j2) {
            const int q = s * 2 + j2;
            const u32 col = cidx[rrow][q];
            const float4* yc = (const float4*)(yf + (nb + col) * CF);
            float a = 0.f;
#pragma unroll
            for (int k = 0; k < 16; ++k) {
                float4 av = yr[k], bv = yc[k];
                a += av.x * bv.x;
                a += av.y * bv.y;
                a += av.z * bv.z;
                a += av.w * bv.w;
            }
            float d2 = (sr + sqlds[col]) - 2.0f * a;
            float dd = sqrtf(fmaxf(d2, 0.0f));
            ckey[rrow][q] = ((u64)__float_as_uint(dd) << 32) | col;
        }
    }
    __syncthreads();

    // phase F: exact top-7 of 32 candidates
    if (tid < 16) {
        u64 t7[KNN];
#pragma unroll
        for (int q = 0; q < KNN; ++q) t7[q] = ~0ull;
#pragma unroll
        for (int q = 0; q < 32; ++q) {
            u64 k = ckey[tid][q];
            if (k < t7[KNN - 1]) insertM64<KNN>(t7, k);
        }
#pragma unroll
        for (int q = 0; q < KNN; ++q)
            cidx[tid][q] = (u32)(t7[q] & 0xFFFFFFFFu);
    }
    __syncthreads();

    // phase O: 7 ones per row (this block's zeros drained at the barriers)
    if (tid < 16 * KNN) {
        const int orow = tid / KNN, q = tid % KNN;
        u32 col = cidx[orow][q];
        adj[(nb + r0 + orow) * NN + col] = 1.0f;
    }
}

// ------------------------------------------------ launcher
extern "C" void kernel_launch(void* const* d_in, const int* in_sizes, int n_in,
                              void* d_out, int out_size, void* d_ws, size_t ws_size,
                              hipStream_t stream) {
    const float* x = (const float*)d_in[0];
    const float* w = (const float*)d_in[1];
    const float* bias = (const float*)d_in[2];

    float* y = (float*)d_out;                               // [4][4096][64]
    float* adj = (float*)d_out + (size_t)BATCH * NN * CF;   // [4][4096][4096]

    float* sq = (float*)d_ws;                               // 64 KB
    u16* ybf = (u16*)((char*)d_ws + 65536);                 // 2 MB tile-major bf16

    conv_fused_kernel<<<4096, 256, 0, stream>>>(x, w, bias, y, ybf, sq);
    screen_kernel<<<1024, 256, 0, stream>>>(ybf, y, sq, adj);
}